// Round 1
// baseline (16986.354 us; speedup 1.0000x reference)
//
#include <hip/hip_runtime.h>
#include <math.h>

#define BATCH 128
#define PATT 36
#define P_TOT 37
#define FDIM 2048
#define EDIM 1024
#define DDIM 1024
#define ADIM 1024
#define VOCAB 10000
#define LCAP 20
#define TSTEPS 19

#define BK 16
#define BM 32
#define BN 64

// ---------------------------------------------------------------------------
// setup: stable counting sort by descending length; write int outputs
// ---------------------------------------------------------------------------
__global__ void setup_kernel(const int* __restrict__ cap_len,   // (B,1)
                             const int* __restrict__ enc_caps,  // (B,L)
                             int* __restrict__ sort_ind, int* __restrict__ dec_len,
                             float* __restrict__ out_enc, float* __restrict__ out_dec,
                             float* __restrict__ out_si) {
  __shared__ int s_ind[BATCH];
  if (threadIdx.x == 0) {
    int pos = 0;
    for (int v = 63; v >= 0 && pos < BATCH; --v) {
      for (int i = 0; i < BATCH; ++i)
        if (cap_len[i] == v) s_ind[pos++] = i;
    }
  }
  __syncthreads();
  for (int i = threadIdx.x; i < BATCH; i += blockDim.x) {
    int si = s_ind[i];
    sort_ind[i] = si;
    int dl = cap_len[si] - 1;
    dec_len[i] = dl;
    out_dec[i] = (float)dl;
    out_si[i] = (float)si;
  }
  for (int i = threadIdx.x; i < BATCH * LCAP; i += blockDim.x) {
    int b = i / LCAP, l = i - b * LCAP;
    out_enc[i] = (float)enc_caps[s_ind[b] * LCAP + l];
  }
}

// ---------------------------------------------------------------------------
// generic GEMM tile: C[m, n] = sum_k X[m, k] * W(n, k) + bias, with W split as
// [Wa (N x Ka) | Wb (N x Kb)] along K.  BM=32, BN=64, 256 threads, 2x4/thread.
// ---------------------------------------------------------------------------
__device__ __forceinline__ void gemm_tile(
    float Xs[BK][BM + 2], float Ws[BK][BN + 4],
    const float* __restrict__ X, int ldx,
    const float* __restrict__ Wa, int Ka,
    const float* __restrict__ Wb, int Kb,
    const float* __restrict__ bias1, const float* __restrict__ bias2,
    float* __restrict__ C, int ldc, int bm, int bn, int N, int relu,
    const int* __restrict__ dec_len, int t)
{
  int tid = threadIdx.x;
  int tm = (tid >> 4) * 2;       // 0..30
  int tn = (tid & 15) * 4;       // 0..60
  int mL = tid >> 3;             // 0..31
  int kL = (tid & 7) * 2;        // 0..14 (even)
  int nL = tid >> 2;             // 0..63
  int kW = (tid & 3) * 4;        // 0,4,8,12
  float acc[2][4] = {{0.f,0.f,0.f,0.f},{0.f,0.f,0.f,0.f}};
  int K = Ka + Kb;
  const float* xptr = X + (size_t)(bm + mL) * ldx + kL;
  int gn_load = bn + nL;
  for (int k0 = 0; k0 < K; k0 += BK) {
    const float* Wp; int ldw, kw;
    if (k0 < Ka) { Wp = Wa; ldw = Ka; kw = k0; }
    else         { Wp = Wb; ldw = Kb; kw = k0 - Ka; }
    float2 xv = *(const float2*)(xptr + k0);
    float4 wv = make_float4(0.f, 0.f, 0.f, 0.f);
    if (gn_load < N) wv = *(const float4*)(Wp + (size_t)gn_load * ldw + kw + kW);
    __syncthreads();
    Xs[kL][mL] = xv.x;  Xs[kL + 1][mL] = xv.y;
    Ws[kW][nL] = wv.x; Ws[kW + 1][nL] = wv.y; Ws[kW + 2][nL] = wv.z; Ws[kW + 3][nL] = wv.w;
    __syncthreads();
#pragma unroll
    for (int kk = 0; kk < BK; ++kk) {
      float2 a = *(const float2*)&Xs[kk][tm];
      float4 b = *(const float4*)&Ws[kk][tn];
      acc[0][0] = fmaf(a.x, b.x, acc[0][0]);
      acc[0][1] = fmaf(a.x, b.y, acc[0][1]);
      acc[0][2] = fmaf(a.x, b.z, acc[0][2]);
      acc[0][3] = fmaf(a.x, b.w, acc[0][3]);
      acc[1][0] = fmaf(a.y, b.x, acc[1][0]);
      acc[1][1] = fmaf(a.y, b.y, acc[1][1]);
      acc[1][2] = fmaf(a.y, b.z, acc[1][2]);
      acc[1][3] = fmaf(a.y, b.w, acc[1][3]);
    }
  }
#pragma unroll
  for (int i = 0; i < 2; ++i) {
    int gm = bm + tm + i;
    bool act = (dec_len == nullptr) || (t < dec_len[gm]);
#pragma unroll
    for (int j = 0; j < 4; ++j) {
      int gn = bn + tn + j;
      if (gn < N) {
        float v = acc[i][j] + bias1[gn] + (bias2 ? bias2[gn] : 0.f);
        if (relu) v = fmaxf(v, 0.f);
        C[(size_t)gm * ldc + gn] = act ? v : 0.f;
      }
    }
  }
}

__global__ __launch_bounds__(256) void gemm_kernel(
    const float* __restrict__ X, int ldx,
    const float* __restrict__ Wa, int Ka,
    const float* __restrict__ Wb, int Kb,
    const float* __restrict__ bias1, const float* __restrict__ bias2,
    float* __restrict__ C, int ldc, int N, int relu,
    const int* __restrict__ dec_len, int t)
{
  __shared__ float Xs[BK][BM + 2];
  __shared__ float Ws[BK][BN + 4];
  gemm_tile(Xs, Ws, X, ldx, Wa, Ka, Wb, Kb, bias1, bias2, C, ldc,
            blockIdx.x * BM, blockIdx.y * BN, N, relu, dec_len, t);
}

// hid = relu([h1 @ Wlang^T + blang | h2 @ Watt^T + batt]) in one launch
__global__ __launch_bounds__(256) void hid_gemm_kernel(
    const float* __restrict__ h1, const float* __restrict__ Wlang, const float* __restrict__ blang,
    const float* __restrict__ h2, const float* __restrict__ Watt, const float* __restrict__ batt,
    float* __restrict__ hid)
{
  __shared__ float Xs[BK][BM + 2];
  __shared__ float Ws[BK][BN + 4];
  int ny = blockIdx.y;
  const float* X; const float* W; const float* bias; int coff;
  if (ny < 8) { X = h1; W = Wlang; bias = blang; coff = 0; }
  else        { X = h2; W = Watt;  bias = batt;  coff = 512; ny -= 8; }
  gemm_tile(Xs, Ws, X, 1024, W, 1024, nullptr, 0, bias, nullptr,
            hid + coff, 1024, blockIdx.x * BM, ny * BN, 512, 1, nullptr, 0);
}

// att1 = concat(img_att, img_fc, axis=1) @ Wfa^T + bfa   (unsorted batch order)
__global__ __launch_bounds__(256) void att1_gemm_kernel(
    const float* __restrict__ img_att, const float* __restrict__ img_fc,
    const float* __restrict__ Wfa, const float* __restrict__ bfa,
    float* __restrict__ att1)
{
  __shared__ float Xs[BK][BM + 2];
  __shared__ float Ws[BK][BN + 4];
  int bm = blockIdx.x * BM, bn = blockIdx.y * BN;
  int tid = threadIdx.x;
  int tm = (tid >> 4) * 2, tn = (tid & 15) * 4;
  int mL = tid >> 3, kL = (tid & 7) * 2;
  int nL = tid >> 2, kW = (tid & 3) * 4;
  int gmr = bm + mL;
  int b = gmr / P_TOT, p = gmr - b * P_TOT;
  const float* xrow = (p < PATT) ? (img_att + ((size_t)b * PATT + p) * FDIM)
                                 : (img_fc + (size_t)b * FDIM);
  float acc[2][4] = {{0.f,0.f,0.f,0.f},{0.f,0.f,0.f,0.f}};
  for (int k0 = 0; k0 < FDIM; k0 += BK) {
    float2 xv = *(const float2*)(xrow + k0 + kL);
    float4 wv = *(const float4*)(Wfa + (size_t)(bn + nL) * FDIM + k0 + kW);
    __syncthreads();
    Xs[kL][mL] = xv.x;  Xs[kL + 1][mL] = xv.y;
    Ws[kW][nL] = wv.x; Ws[kW + 1][nL] = wv.y; Ws[kW + 2][nL] = wv.z; Ws[kW + 3][nL] = wv.w;
    __syncthreads();
#pragma unroll
    for (int kk = 0; kk < BK; ++kk) {
      float2 a = *(const float2*)&Xs[kk][tm];
      float4 v = *(const float4*)&Ws[kk][tn];
      acc[0][0] = fmaf(a.x, v.x, acc[0][0]);
      acc[0][1] = fmaf(a.x, v.y, acc[0][1]);
      acc[0][2] = fmaf(a.x, v.z, acc[0][2]);
      acc[0][3] = fmaf(a.x, v.w, acc[0][3]);
      acc[1][0] = fmaf(a.y, v.x, acc[1][0]);
      acc[1][1] = fmaf(a.y, v.y, acc[1][1]);
      acc[1][2] = fmaf(a.y, v.z, acc[1][2]);
      acc[1][3] = fmaf(a.y, v.w, acc[1][3]);
    }
  }
#pragma unroll
  for (int i = 0; i < 2; ++i) {
    int gm = bm + tm + i;
#pragma unroll
    for (int j = 0; j < 4; ++j) {
      int gn = bn + tn + j;
      att1[(size_t)gm * ADIM + gn] = acc[i][j] + bfa[gn];
    }
  }
}

// x1cat = [emb[cap_t] | h2 | img_fc_sorted | h1]  (K layout for [Wll_ih | Wll_hh])
__global__ void build_x1_kernel(const float* __restrict__ emb, const int* __restrict__ enc_caps,
                                const int* __restrict__ sort_ind, const float* __restrict__ img_fc,
                                const float* __restrict__ h1, const float* __restrict__ h2,
                                float* __restrict__ x1cat, int t) {
  int b = blockIdx.x;
  int si = sort_ind[b];
  int cap = enc_caps[si * LCAP + t];
  const float* erow = emb + (size_t)cap * EDIM;
  float* dst = x1cat + (size_t)b * (EDIM + DDIM + FDIM + DDIM);
  for (int k = threadIdx.x; k < EDIM; k += blockDim.x) dst[k] = erow[k];
  for (int k = threadIdx.x; k < DDIM; k += blockDim.x) dst[EDIM + k] = h2[b * DDIM + k];
  for (int k = threadIdx.x; k < FDIM; k += blockDim.x) dst[EDIM + DDIM + k] = img_fc[(size_t)si * FDIM + k];
  for (int k = threadIdx.x; k < DDIM; k += blockDim.x) dst[EDIM + DDIM + FDIM + k] = h1[b * DDIM + k];
}

// LSTM cell elementwise; masked carry update; optionally emit hcat=[h_new|h_other_old]
__global__ void lstm_cell_kernel(const float* __restrict__ gates,
                                 float* __restrict__ h, float* __restrict__ c,
                                 const int* __restrict__ dec_len, int t,
                                 float* __restrict__ hcat, const float* __restrict__ h_other) {
  int idx = blockIdx.x * blockDim.x + threadIdx.x;   // 0 .. B*D
  int b = idx >> 10, j = idx & 1023;
  const float* g = gates + (size_t)b * 4096;
  float iv = 1.f / (1.f + expf(-g[j]));
  float fv = 1.f / (1.f + expf(-g[1024 + j]));
  float gv = tanhf(g[2048 + j]);
  float ov = 1.f / (1.f + expf(-g[3072 + j]));
  float cn = fv * c[idx] + iv * gv;
  float hn = ov * tanhf(cn);
  bool act = t < dec_len[b];
  float hw = act ? hn : h[idx];
  float cw = act ? cn : c[idx];
  h[idx] = hw; c[idx] = cw;
  if (hcat) {
    hcat[b * 2048 + j] = hw;
    hcat[b * 2048 + 1024 + j] = h_other[idx];
  }
}

// attention: scores->softmax->alphas out->awe; also writes x2cat=[awe|h2old]
__global__ __launch_bounds__(256) void attention_kernel(
    const float* __restrict__ att1, const float* __restrict__ d12,
    const float* __restrict__ Wfull, const float* __restrict__ bfull,
    const float* __restrict__ img_att, const float* __restrict__ img_fc,
    const int* __restrict__ sort_ind, const int* __restrict__ dec_len,
    float* __restrict__ x2cat, const float* __restrict__ h2,
    float* __restrict__ out_alphas, int t) {
  int b = blockIdx.x;
  int si = sort_ind[b];
  __shared__ float dsh[ADIM];
  __shared__ float sc[P_TOT];
  __shared__ float al[P_TOT];
  int tid = threadIdx.x;
  for (int k = tid; k < ADIM; k += 256) dsh[k] = d12[b * ADIM + k];
  __syncthreads();
  int wave = tid >> 6, lane = tid & 63;
  for (int p = wave; p < P_TOT; p += 4) {
    const float* arow = att1 + ((size_t)si * P_TOT + p) * ADIM;
    float s = 0.f;
    for (int k = lane; k < ADIM; k += 64) {
      float e = fmaxf(arow[k] + dsh[k], 0.f);
      s += e * Wfull[k];
    }
    for (int off = 32; off; off >>= 1) s += __shfl_down(s, off, 64);
    if (lane == 0) sc[p] = s + bfull[0];
  }
  __syncthreads();
  if (tid == 0) {
    float mx = sc[0];
    for (int p = 1; p < P_TOT; ++p) mx = fmaxf(mx, sc[p]);
    float sum = 0.f;
    for (int p = 0; p < P_TOT; ++p) { float e = expf(sc[p] - mx); al[p] = e; sum += e; }
    float inv = 1.f / sum;
    for (int p = 0; p < P_TOT; ++p) al[p] *= inv;
  }
  __syncthreads();
  bool act = t < dec_len[b];
  if (tid < P_TOT)
    out_alphas[((size_t)b * TSTEPS + t) * P_TOT + tid] = act ? al[tid] : 0.f;
  for (int f = tid; f < FDIM; f += 256) {
    float s = 0.f;
#pragma unroll 4
    for (int p = 0; p < PATT; ++p) s += al[p] * img_att[((size_t)si * PATT + p) * FDIM + f];
    s += al[PATT] * img_fc[(size_t)si * FDIM + f];
    x2cat[(size_t)b * (FDIM + DDIM) + f] = s;
  }
  for (int j = tid; j < DDIM; j += 256)
    x2cat[(size_t)b * (FDIM + DDIM) + FDIM + j] = h2[b * DDIM + j];
}

// ---------------------------------------------------------------------------
extern "C" void kernel_launch(void* const* d_in, const int* in_sizes, int n_in,
                              void* d_out, int out_size, void* d_ws, size_t ws_size,
                              hipStream_t stream) {
  const float* img_att = (const float*)d_in[0];
  const float* img_fc  = (const float*)d_in[1];
  const int*   enc_caps= (const int*)d_in[2];
  const int*   cap_len = (const int*)d_in[3];
  const float* emb     = (const float*)d_in[4];
  const float* Wfa     = (const float*)d_in[5];
  const float* bfa     = (const float*)d_in[6];
  const float* Wd1     = (const float*)d_in[7];
  const float* bd1     = (const float*)d_in[8];
  const float* Wd2     = (const float*)d_in[9];
  const float* bd2     = (const float*)d_in[10];
  const float* Wfull   = (const float*)d_in[11];
  const float* bfull   = (const float*)d_in[12];
  const float* Wlang   = (const float*)d_in[13];
  const float* blang   = (const float*)d_in[14];
  const float* Watt    = (const float*)d_in[15];
  const float* batt    = (const float*)d_in[16];
  const float* Wout    = (const float*)d_in[17];
  const float* bout    = (const float*)d_in[18];
  const float* Wll_ih  = (const float*)d_in[19];
  const float* Wll_hh  = (const float*)d_in[20];
  const float* bll     = (const float*)d_in[21];
  const float* Wal_ih  = (const float*)d_in[22];
  const float* Wal_hh  = (const float*)d_in[23];
  const float* bal     = (const float*)d_in[24];
  const float* Wfc     = (const float*)d_in[25];
  const float* bfc     = (const float*)d_in[26];

  // workspace layout
  int* sort_ind = (int*)d_ws;
  int* dec_len  = sort_ind + BATCH;
  float* base = (float*)d_ws + 256;
  const size_t BD = (size_t)BATCH * DDIM;           // 131072
  float* h1    = base;
  float* c1    = h1 + BD;
  float* h2    = c1 + BD;
  float* c2    = h2 + BD;
  float* x1cat = c2 + BD;                           // B x 5120
  float* gates = x1cat + (size_t)BATCH * 5120;      // B x 4096
  float* d12   = gates + (size_t)BATCH * 4096;      // B x 1024
  float* hcat  = d12 + BD;                          // B x 2048
  float* x2cat = hcat + (size_t)BATCH * 2048;       // B x 3072
  float* hid   = x2cat + (size_t)BATCH * 3072;      // B x 1024
  float* att1  = hid + BD;                          // B x 37 x 1024

  // output layout
  float* out      = (float*)d_out;
  float* out_pred = out;
  float* out_pred1= out_pred  + (size_t)BATCH * TSTEPS * VOCAB;
  float* out_enc  = out_pred1 + (size_t)BATCH * TSTEPS * VOCAB;
  float* out_dec  = out_enc + (size_t)BATCH * LCAP;
  float* out_alph = out_dec + BATCH;
  float* out_si   = out_alph + (size_t)BATCH * TSTEPS * P_TOT;

  setup_kernel<<<1, 256, 0, stream>>>(cap_len, enc_caps, sort_ind, dec_len,
                                      out_enc, out_dec, out_si);
  hipMemsetAsync(h1, 0, 4 * BD * sizeof(float), stream);
  att1_gemm_kernel<<<dim3((BATCH * P_TOT) / BM, ADIM / BN), 256, 0, stream>>>(
      img_att, img_fc, Wfa, bfa, att1);

  const int ldo = TSTEPS * VOCAB;
  for (int t = 0; t < TSTEPS; ++t) {
    build_x1_kernel<<<BATCH, 256, 0, stream>>>(emb, enc_caps, sort_ind, img_fc,
                                               h1, h2, x1cat, t);
    // gates1 = x1cat @ [Wll_ih|Wll_hh]^T + bll
    gemm_kernel<<<dim3(BATCH / BM, 4096 / BN), 256, 0, stream>>>(
        x1cat, 5120, Wll_ih, 4096, Wll_hh, 1024, bll, nullptr,
        gates, 4096, 4096, 0, nullptr, 0);
    lstm_cell_kernel<<<(BATCH * DDIM) / 256, 256, 0, stream>>>(
        gates, h1, c1, dec_len, t, hcat, h2);
    // preds1 = h1 @ Wfc^T + bfc  (masked store to output slice)
    gemm_kernel<<<dim3(BATCH / BM, (VOCAB + BN - 1) / BN), 256, 0, stream>>>(
        h1, 1024, Wfc, 1024, nullptr, 0, bfc, nullptr,
        out_pred1 + (size_t)t * VOCAB, ldo, VOCAB, 0, dec_len, t);
    // d12 = h1 @ Wd1^T + h2old @ Wd2^T + bd1 + bd2
    gemm_kernel<<<dim3(BATCH / BM, 1024 / BN), 256, 0, stream>>>(
        hcat, 2048, Wd1, 1024, Wd2, 1024, bd1, bd2,
        d12, 1024, 1024, 0, nullptr, 0);
    attention_kernel<<<BATCH, 256, 0, stream>>>(
        att1, d12, Wfull, bfull, img_att, img_fc, sort_ind, dec_len,
        x2cat, h2, out_alph, t);
    // gates2 = [awe|h2old] @ [Wal_ih|Wal_hh]^T + bal
    gemm_kernel<<<dim3(BATCH / BM, 4096 / BN), 256, 0, stream>>>(
        x2cat, 3072, Wal_ih, 2048, Wal_hh, 1024, bal, nullptr,
        gates, 4096, 4096, 0, nullptr, 0);
    lstm_cell_kernel<<<(BATCH * DDIM) / 256, 256, 0, stream>>>(
        gates, h2, c2, dec_len, t, nullptr, nullptr);
    hid_gemm_kernel<<<dim3(BATCH / BM, 16), 256, 0, stream>>>(
        h1, Wlang, blang, h2, Watt, batt, hid);
    // out = hid @ Wout^T + bout  (masked store to output slice)
    gemm_kernel<<<dim3(BATCH / BM, (VOCAB + BN - 1) / BN), 256, 0, stream>>>(
        hid, 1024, Wout, 1024, nullptr, 0, bout, nullptr,
        out_pred + (size_t)t * VOCAB, ldo, VOCAB, 0, dec_len, t);
  }
}

// Round 2
// 8281.747 us; speedup vs baseline: 2.0511x; 2.0511x over previous
//
#include <hip/hip_runtime.h>
#include <math.h>

#define BATCH 128
#define PATT 36
#define P_TOT 37
#define FDIM 2048
#define EDIM 1024
#define DDIM 1024
#define ADIM 1024
#define VOCAB 10000
#define LCAP 20
#define TSTEPS 19

typedef __attribute__((ext_vector_type(8))) short bf16x8v;
typedef __attribute__((ext_vector_type(4))) float f32x4v;

__device__ __forceinline__ ushort f2bf(float f) {
  unsigned u = __float_as_uint(f);
  unsigned r = (u + 0x7fffu + ((u >> 16) & 1u)) >> 16;   // RNE
  return (ushort)r;
}
__device__ __forceinline__ float bf2f(ushort u) {
  return __uint_as_float(((unsigned)u) << 16);
}

// ---------------------------------------------------------------------------
// setup: stable counting sort by descending length; write int-ish outputs
// ---------------------------------------------------------------------------
__global__ void setup_kernel(const int* __restrict__ cap_len,
                             const int* __restrict__ enc_caps,
                             int* __restrict__ sort_ind, int* __restrict__ dec_len,
                             float* __restrict__ out_enc, float* __restrict__ out_dec,
                             float* __restrict__ out_si) {
  __shared__ int s_ind[BATCH];
  if (threadIdx.x == 0) {
    int pos = 0;
    for (int v = 63; v >= 0 && pos < BATCH; --v)
      for (int i = 0; i < BATCH; ++i)
        if (cap_len[i] == v) s_ind[pos++] = i;
  }
  __syncthreads();
  for (int i = threadIdx.x; i < BATCH; i += blockDim.x) {
    int si = s_ind[i];
    sort_ind[i] = si;
    int dl = cap_len[si] - 1;
    dec_len[i] = dl;
    out_dec[i] = (float)dl;
    out_si[i] = (float)si;
  }
  for (int i = threadIdx.x; i < BATCH * LCAP; i += blockDim.x) {
    int b = i / LCAP, l = i - b * LCAP;
    out_enc[i] = (float)enc_caps[s_ind[b] * LCAP + l];
  }
}

// ---------------------------------------------------------------------------
// fp32 -> bf16 weight conversion, segmented
// ---------------------------------------------------------------------------
struct Seg { const float* src; ushort* dst; unsigned n; };
struct SegTab { Seg s[11]; };

__global__ __launch_bounds__(256) void convert_kernel(SegTab tab) {
  Seg sg = tab.s[blockIdx.y];
  unsigned i0 = (blockIdx.x * 256u + threadIdx.x) * 8u;
  if (i0 >= sg.n) return;
  float4 f0 = *(const float4*)(sg.src + i0);
  float4 f1 = *(const float4*)(sg.src + i0 + 4);
  ushort r[8];
  r[0] = f2bf(f0.x); r[1] = f2bf(f0.y); r[2] = f2bf(f0.z); r[3] = f2bf(f0.w);
  r[4] = f2bf(f1.x); r[5] = f2bf(f1.y); r[6] = f2bf(f1.z); r[7] = f2bf(f1.w);
  *(uint4*)(sg.dst + i0) = *(uint4*)r;
}

// img_cat[b*37+p][:] = bf16(concat(img_att, img_fc)[b][p][:])
__global__ __launch_bounds__(256) void img_cat_kernel(const float* __restrict__ img_att,
                                                      const float* __restrict__ img_fc,
                                                      ushort* __restrict__ img_cat) {
  int b = blockIdx.x, p = blockIdx.y;
  const float* src = (p < PATT) ? img_att + ((size_t)b * PATT + p) * FDIM
                                : img_fc + (size_t)b * FDIM;
  ushort* dst = img_cat + ((size_t)b * P_TOT + p) * FDIM;
  int i0 = threadIdx.x * 8;
  float4 f0 = *(const float4*)(src + i0);
  float4 f1 = *(const float4*)(src + i0 + 4);
  ushort r[8];
  r[0] = f2bf(f0.x); r[1] = f2bf(f0.y); r[2] = f2bf(f0.z); r[3] = f2bf(f0.w);
  r[4] = f2bf(f1.x); r[5] = f2bf(f1.y); r[6] = f2bf(f1.z); r[7] = f2bf(f1.w);
  *(uint4*)(dst + i0) = *(uint4*)r;
}

// ---------------------------------------------------------------------------
// bf16 MFMA GEMM: C[m,n] = sum_k X[m,k]*W(n,k) + bias1(+bias2), W=[Wa|Wb] in K.
// Block 256 thr = 4 waves (2x2), tile 128M x 64N, K-chunk 64 staged in LDS.
// Optional relu, row-mask (zero where t>=dec_len[m]), fp32 C and/or bf16 Cb.
// ---------------------------------------------------------------------------
__global__ __launch_bounds__(256) void gemm_mfma_kernel(
    const ushort* __restrict__ X, int ldx,
    const ushort* __restrict__ Wa, int Ka,
    const ushort* __restrict__ Wb, int Kb,
    const float* __restrict__ bias1, const float* __restrict__ bias2,
    float* __restrict__ C, ushort* __restrict__ Cb, long ldc,
    int N, int relu, const int* __restrict__ dec_len, int t)
{
  __shared__ __align__(16) ushort As[128][72];
  __shared__ __align__(16) ushort Bs[64][72];

  const int tid = threadIdx.x;
  const int lane = tid & 63;
  const int wv = tid >> 6;
  const int wm = wv >> 1;          // 0..1 : m-half (64 rows)
  const int wn = wv & 1;           // 0..1 : n-half (32 cols)
  const int q = lane >> 4;         // quad 0..3
  const int c16 = lane & 15;

  const int bm = blockIdx.x * 128;
  const int bn = blockIdx.y * 64;
  const int K = Ka + Kb;

  f32x4v acc[4][2];
#pragma unroll
  for (int i = 0; i < 4; ++i)
#pragma unroll
    for (int j = 0; j < 2; ++j) acc[i][j] = (f32x4v){0.f, 0.f, 0.f, 0.f};

  for (int k0 = 0; k0 < K; k0 += 64) {
    __syncthreads();
    // stage A: 128 rows x 8 granules(16B)
#pragma unroll
    for (int i = 0; i < 4; ++i) {
      int idx = i * 256 + tid;
      int r = idx >> 3, g = idx & 7;
      const ushort* src = X + (size_t)(bm + r) * ldx + k0 + g * 8;
      *(uint4*)&As[r][g * 8] = *(const uint4*)src;
    }
    // stage B: 64 rows x 8 granules
#pragma unroll
    for (int i = 0; i < 2; ++i) {
      int idx = i * 256 + tid;
      int r = idx >> 3, g = idx & 7;
      int gn = bn + r;
      int kk = k0 + g * 8;
      uint4 val = {0u, 0u, 0u, 0u};
      if (gn < N) {
        const ushort* src = (kk < Ka) ? Wa + (size_t)gn * Ka + kk
                                      : Wb + (size_t)gn * Kb + (kk - Ka);
        val = *(const uint4*)src;
      }
      *(uint4*)&Bs[r][g * 8] = val;
    }
    __syncthreads();
#pragma unroll
    for (int ks = 0; ks < 2; ++ks) {
      const int kcol = ks * 32 + q * 8;
      bf16x8v a[4], b[2];
#pragma unroll
      for (int mf = 0; mf < 4; ++mf)
        a[mf] = *(const bf16x8v*)&As[wm * 64 + mf * 16 + c16][kcol];
#pragma unroll
      for (int nf = 0; nf < 2; ++nf)
        b[nf] = *(const bf16x8v*)&Bs[wn * 32 + nf * 16 + c16][kcol];
#pragma unroll
      for (int mf = 0; mf < 4; ++mf)
#pragma unroll
        for (int nf = 0; nf < 2; ++nf)
          acc[mf][nf] = __builtin_amdgcn_mfma_f32_16x16x32_bf16(a[mf], b[nf], acc[mf][nf], 0, 0, 0);
    }
  }

  // epilogue: C/D layout col=lane&15, row=quad*4+reg
#pragma unroll
  for (int nf = 0; nf < 2; ++nf) {
    int gcol = bn + wn * 32 + nf * 16 + c16;
    if (gcol >= N) continue;
    float bsum = bias1[gcol] + (bias2 ? bias2[gcol] : 0.f);
#pragma unroll
    for (int mf = 0; mf < 4; ++mf) {
#pragma unroll
      for (int rr = 0; rr < 4; ++rr) {
        int grow = bm + wm * 64 + mf * 16 + q * 4 + rr;
        float v = acc[mf][nf][rr] + bsum;
        if (relu) v = fmaxf(v, 0.f);
        if (dec_len && !(t < dec_len[grow])) v = 0.f;
        if (C)  C[(size_t)grow * ldc + gcol] = v;
        if (Cb) Cb[(size_t)grow * ldc + gcol] = f2bf(v);
      }
    }
  }
}

// ---------------------------------------------------------------------------
// x1cat(bf16) = [emb[cap_t] | h2old | img_fc_sorted | h1old]
// ---------------------------------------------------------------------------
__global__ void build_x1_kernel(const float* __restrict__ emb, const int* __restrict__ enc_caps,
                                const int* __restrict__ sort_ind, const ushort* __restrict__ img_cat,
                                const ushort* __restrict__ h1bf, const ushort* __restrict__ h2bf,
                                ushort* __restrict__ x1cat, int t) {
  int b = blockIdx.x;
  int si = sort_ind[b];
  int cap = enc_caps[si * LCAP + t];
  const float* erow = emb + (size_t)cap * EDIM;
  const ushort* fcrow = img_cat + ((size_t)si * P_TOT + PATT) * FDIM;
  ushort* dst = x1cat + (size_t)b * 5120;
  for (int k = threadIdx.x; k < EDIM; k += 256) dst[k] = f2bf(erow[k]);
  for (int k = threadIdx.x; k < DDIM; k += 256) dst[EDIM + k] = h2bf[b * DDIM + k];
  for (int k = threadIdx.x; k < FDIM; k += 256) dst[EDIM + DDIM + k] = fcrow[k];
  for (int k = threadIdx.x; k < DDIM; k += 256) dst[EDIM + DDIM + FDIM + k] = h1bf[b * DDIM + k];
}

// ---------------------------------------------------------------------------
// LSTM cell; masked carry; bf16 mirror; optional hcat=[h_new|h_other_old]
// ---------------------------------------------------------------------------
__global__ void lstm_cell_kernel(const float* __restrict__ gates,
                                 float* __restrict__ h, float* __restrict__ c,
                                 const int* __restrict__ dec_len, int t,
                                 ushort* __restrict__ hbf,
                                 ushort* __restrict__ hcat, const ushort* __restrict__ h_other_bf) {
  int idx = blockIdx.x * blockDim.x + threadIdx.x;
  int b = idx >> 10, j = idx & 1023;
  const float* g = gates + (size_t)b * 4096;
  float iv = 1.f / (1.f + expf(-g[j]));
  float fv = 1.f / (1.f + expf(-g[1024 + j]));
  float gv = tanhf(g[2048 + j]);
  float ov = 1.f / (1.f + expf(-g[3072 + j]));
  float cn = fv * c[idx] + iv * gv;
  float hn = ov * tanhf(cn);
  bool act = t < dec_len[b];
  float hw = act ? hn : h[idx];
  float cw = act ? cn : c[idx];
  h[idx] = hw; c[idx] = cw;
  hbf[idx] = f2bf(hw);
  if (hcat) {
    hcat[b * 2048 + j] = f2bf(hw);
    hcat[b * 2048 + 1024 + j] = h_other_bf[idx];
  }
}

// ---------------------------------------------------------------------------
// attention: scores -> softmax -> alphas out (masked) -> awe; x2cat=[awe|h2old]
// ---------------------------------------------------------------------------
__global__ __launch_bounds__(256) void attention_kernel(
    const ushort* __restrict__ att1, const float* __restrict__ d12,
    const float* __restrict__ Wfull, const float* __restrict__ bfull,
    const ushort* __restrict__ img_cat,
    const int* __restrict__ sort_ind, const int* __restrict__ dec_len,
    ushort* __restrict__ x2cat, const ushort* __restrict__ h2bf,
    float* __restrict__ out_alphas, int t) {
  int b = blockIdx.x;
  int si = sort_ind[b];
  __shared__ float dsh[ADIM];
  __shared__ float sc[P_TOT];
  __shared__ float al[P_TOT + 3];
  int tid = threadIdx.x;
  for (int k = tid; k < ADIM; k += 256) dsh[k] = d12[b * ADIM + k];
  __syncthreads();
  int wave = tid >> 6, lane = tid & 63;
  for (int p = wave; p < P_TOT; p += 4) {
    const ushort* arow = att1 + ((size_t)si * P_TOT + p) * ADIM;
    float s = 0.f;
    for (int k = lane * 4; k < ADIM; k += 256) {
      ushort4 av = *(const ushort4*)&arow[k];
      float e0 = fmaxf(bf2f(av.x) + dsh[k + 0], 0.f);
      float e1 = fmaxf(bf2f(av.y) + dsh[k + 1], 0.f);
      float e2 = fmaxf(bf2f(av.z) + dsh[k + 2], 0.f);
      float e3 = fmaxf(bf2f(av.w) + dsh[k + 3], 0.f);
      s += e0 * Wfull[k] + e1 * Wfull[k + 1] + e2 * Wfull[k + 2] + e3 * Wfull[k + 3];
    }
    for (int off = 32; off; off >>= 1) s += __shfl_down(s, off, 64);
    if (lane == 0) sc[p] = s + bfull[0];
  }
  __syncthreads();
  if (tid == 0) {
    float mx = sc[0];
    for (int p = 1; p < P_TOT; ++p) mx = fmaxf(mx, sc[p]);
    float sum = 0.f;
    for (int p = 0; p < P_TOT; ++p) { float e = expf(sc[p] - mx); al[p] = e; sum += e; }
    float inv = 1.f / sum;
    for (int p = 0; p < P_TOT; ++p) al[p] *= inv;
  }
  __syncthreads();
  bool act = t < dec_len[b];
  if (tid < P_TOT)
    out_alphas[((size_t)b * TSTEPS + t) * P_TOT + tid] = act ? al[tid] : 0.f;
  // awe: 2048 floats, 4 per thread x 2 iters
  for (int f0 = tid * 4; f0 < FDIM; f0 += 1024) {
    float a0 = 0.f, a1 = 0.f, a2 = 0.f, a3 = 0.f;
#pragma unroll 4
    for (int p = 0; p < P_TOT; ++p) {
      ushort4 iv = *(const ushort4*)&img_cat[((size_t)si * P_TOT + p) * FDIM + f0];
      float w = al[p];
      a0 += w * bf2f(iv.x); a1 += w * bf2f(iv.y);
      a2 += w * bf2f(iv.z); a3 += w * bf2f(iv.w);
    }
    ushort* dst = x2cat + (size_t)b * 3072 + f0;
    dst[0] = f2bf(a0); dst[1] = f2bf(a1); dst[2] = f2bf(a2); dst[3] = f2bf(a3);
  }
  for (int j = tid; j < DDIM; j += 256)
    x2cat[(size_t)b * 3072 + FDIM + j] = h2bf[b * DDIM + j];
}

// ---------------------------------------------------------------------------
extern "C" void kernel_launch(void* const* d_in, const int* in_sizes, int n_in,
                              void* d_out, int out_size, void* d_ws, size_t ws_size,
                              hipStream_t stream) {
  const float* img_att = (const float*)d_in[0];
  const float* img_fc  = (const float*)d_in[1];
  const int*   enc_caps= (const int*)d_in[2];
  const int*   cap_len = (const int*)d_in[3];
  const float* emb     = (const float*)d_in[4];
  const float* Wfa     = (const float*)d_in[5];
  const float* bfa     = (const float*)d_in[6];
  const float* Wd1     = (const float*)d_in[7];
  const float* bd1     = (const float*)d_in[8];
  const float* Wd2     = (const float*)d_in[9];
  const float* bd2     = (const float*)d_in[10];
  const float* Wfull   = (const float*)d_in[11];
  const float* bfull   = (const float*)d_in[12];
  const float* Wlang   = (const float*)d_in[13];
  const float* blang   = (const float*)d_in[14];
  const float* Watt    = (const float*)d_in[15];
  const float* batt    = (const float*)d_in[16];
  const float* Wout    = (const float*)d_in[17];
  const float* bout    = (const float*)d_in[18];
  const float* Wll_ih  = (const float*)d_in[19];
  const float* Wll_hh  = (const float*)d_in[20];
  const float* bll     = (const float*)d_in[21];
  const float* Wal_ih  = (const float*)d_in[22];
  const float* Wal_hh  = (const float*)d_in[23];
  const float* bal     = (const float*)d_in[24];
  const float* Wfc     = (const float*)d_in[25];
  const float* bfc     = (const float*)d_in[26];

  // ---- workspace layout ----
  int* sort_ind = (int*)d_ws;
  int* dec_len  = sort_ind + BATCH;
  float* fbase = (float*)d_ws + 256;
  const size_t BD = (size_t)BATCH * DDIM;
  float* h1    = fbase;              // 131072
  float* c1    = h1 + BD;
  float* h2    = c1 + BD;
  float* c2    = h2 + BD;
  float* gates = c2 + BD;            // 524288
  float* d12   = gates + (size_t)BATCH * 4096;   // 131072
  ushort* ubase = (ushort*)(d12 + BD);
  ushort* h1bf   = ubase;                          // 131072
  ushort* h2bf   = h1bf + BD;                      // 131072
  ushort* x1cat  = h2bf + BD;                      // 655360
  ushort* hcat   = x1cat + (size_t)BATCH * 5120;   // 262144
  ushort* x2cat  = hcat + (size_t)BATCH * 2048;    // 393216
  ushort* hid_bf = x2cat + (size_t)BATCH * 3072;   // 131072
  ushort* att1_bf= hid_bf + BD;                    // 4849664
  ushort* img_cat= att1_bf + (size_t)BATCH * P_TOT * ADIM;  // 9699328
  ushort* wb     = img_cat + (size_t)BATCH * P_TOT * FDIM;
  ushort* Wfa_b  = wb;                 wb += (size_t)ADIM * FDIM;
  ushort* Wd1_b  = wb;                 wb += (size_t)ADIM * DDIM;
  ushort* Wd2_b  = wb;                 wb += (size_t)ADIM * DDIM;
  ushort* Wlang_b= wb;                 wb += (size_t)512 * DDIM;
  ushort* Watt_b = wb;                 wb += (size_t)512 * DDIM;
  ushort* Wout_b = wb;                 wb += (size_t)VOCAB * 1024;
  ushort* Wll_ih_b = wb;               wb += (size_t)4096 * 4096;
  ushort* Wll_hh_b = wb;               wb += (size_t)4096 * 1024;
  ushort* Wal_ih_b = wb;               wb += (size_t)4096 * 2048;
  ushort* Wal_hh_b = wb;               wb += (size_t)4096 * 1024;
  ushort* Wfc_b  = wb;                 wb += (size_t)VOCAB * 1024;

  // ---- output layout ----
  float* out      = (float*)d_out;
  float* out_pred = out;
  float* out_pred1= out_pred  + (size_t)BATCH * TSTEPS * VOCAB;
  float* out_enc  = out_pred1 + (size_t)BATCH * TSTEPS * VOCAB;
  float* out_dec  = out_enc + (size_t)BATCH * LCAP;
  float* out_alph = out_dec + BATCH;
  float* out_si   = out_alph + (size_t)BATCH * TSTEPS * P_TOT;

  setup_kernel<<<1, 256, 0, stream>>>(cap_len, enc_caps, sort_ind, dec_len,
                                      out_enc, out_dec, out_si);
  hipMemsetAsync(h1, 0, 4 * BD * sizeof(float), stream);          // h1,c1,h2,c2
  hipMemsetAsync(h1bf, 0, 2 * BD * sizeof(ushort), stream);       // h1bf,h2bf

  SegTab tab;
  tab.s[0]  = {Wfa,    Wfa_b,    (unsigned)(ADIM * FDIM)};
  tab.s[1]  = {Wd1,    Wd1_b,    (unsigned)(ADIM * DDIM)};
  tab.s[2]  = {Wd2,    Wd2_b,    (unsigned)(ADIM * DDIM)};
  tab.s[3]  = {Wlang,  Wlang_b,  (unsigned)(512 * DDIM)};
  tab.s[4]  = {Watt,   Watt_b,   (unsigned)(512 * DDIM)};
  tab.s[5]  = {Wout,   Wout_b,   (unsigned)(VOCAB * 1024)};
  tab.s[6]  = {Wll_ih, Wll_ih_b, (unsigned)(4096 * 4096)};
  tab.s[7]  = {Wll_hh, Wll_hh_b, (unsigned)(4096 * 1024)};
  tab.s[8]  = {Wal_ih, Wal_ih_b, (unsigned)(4096 * 2048)};
  tab.s[9]  = {Wal_hh, Wal_hh_b, (unsigned)(4096 * 1024)};
  tab.s[10] = {Wfc,    Wfc_b,    (unsigned)(VOCAB * 1024)};
  convert_kernel<<<dim3(8192, 11), 256, 0, stream>>>(tab);

  img_cat_kernel<<<dim3(BATCH, P_TOT), 256, 0, stream>>>(img_att, img_fc, img_cat);

  // att1 = img_cat @ Wfa^T + bfa  -> bf16  (M=4736, N=1024, K=2048)
  gemm_mfma_kernel<<<dim3(37, 16), 256, 0, stream>>>(
      img_cat, FDIM, Wfa_b, FDIM, nullptr, 0, bfa, nullptr,
      nullptr, att1_bf, ADIM, ADIM, 0, nullptr, 0);

  const long ldo = (long)TSTEPS * VOCAB;
  for (int t = 0; t < TSTEPS; ++t) {
    build_x1_kernel<<<BATCH, 256, 0, stream>>>(emb, enc_caps, sort_ind, img_cat,
                                               h1bf, h2bf, x1cat, t);
    // gates1 = x1cat @ [Wll_ih|Wll_hh]^T + bll   (N=4096, K=5120)
    gemm_mfma_kernel<<<dim3(1, 64), 256, 0, stream>>>(
        x1cat, 5120, Wll_ih_b, 4096, Wll_hh_b, 1024, bll, nullptr,
        gates, nullptr, 4096, 4096, 0, nullptr, 0);
    lstm_cell_kernel<<<(BATCH * DDIM) / 256, 256, 0, stream>>>(
        gates, h1, c1, dec_len, t, h1bf, hcat, h2bf);
    // preds1 = h1 @ Wfc^T + bfc  (masked, N=10000, K=1024)
    gemm_mfma_kernel<<<dim3(1, 157), 256, 0, stream>>>(
        h1bf, 1024, Wfc_b, 1024, nullptr, 0, bfc, nullptr,
        out_pred1 + (size_t)t * VOCAB, nullptr, ldo, VOCAB, 0, dec_len, t);
    // d12 = [h1|h2old] @ [Wd1|Wd2]^T + bd1 + bd2  (N=1024, K=2048)
    gemm_mfma_kernel<<<dim3(1, 16), 256, 0, stream>>>(
        hcat, 2048, Wd1_b, 1024, Wd2_b, 1024, bd1, bd2,
        d12, nullptr, 1024, 1024, 0, nullptr, 0);
    attention_kernel<<<BATCH, 256, 0, stream>>>(
        att1_bf, d12, Wfull, bfull, img_cat, sort_ind, dec_len,
        x2cat, h2bf, out_alph, t);
    // gates2 = [awe|h2old] @ [Wal_ih|Wal_hh]^T + bal  (N=4096, K=3072)
    gemm_mfma_kernel<<<dim3(1, 64), 256, 0, stream>>>(
        x2cat, 3072, Wal_ih_b, 2048, Wal_hh_b, 1024, bal, nullptr,
        gates, nullptr, 4096, 4096, 0, nullptr, 0);
    lstm_cell_kernel<<<(BATCH * DDIM) / 256, 256, 0, stream>>>(
        gates, h2, c2, dec_len, t, h2bf, nullptr, nullptr);
    // hid = relu([h1 @ Wlang^T + blang | h2 @ Watt^T + batt]) -> bf16
    gemm_mfma_kernel<<<dim3(1, 8), 256, 0, stream>>>(
        h1bf, 1024, Wlang_b, 1024, nullptr, 0, blang, nullptr,
        nullptr, hid_bf, 1024, 512, 1, nullptr, 0);
    gemm_mfma_kernel<<<dim3(1, 8), 256, 0, stream>>>(
        h2bf, 1024, Watt_b, 1024, nullptr, 0, batt, nullptr,
        nullptr, hid_bf + 512, 1024, 512, 1, nullptr, 0);
    // out = hid @ Wout^T + bout  (masked, N=10000, K=1024)
    gemm_mfma_kernel<<<dim3(1, 157), 256, 0, stream>>>(
        hid_bf, 1024, Wout_b, 1024, nullptr, 0, bout, nullptr,
        out_pred + (size_t)t * VOCAB, nullptr, ldo, VOCAB, 0, dec_len, t);
  }
}